// Round 3
// baseline (1685.543 us; speedup 1.0000x reference)
//
#include <hip/hip_runtime.h>
#include <math.h>

// CTRNN + adaptive DOPRI5 (B=2048, N=1024). Round 3: single persistent
// kernel, 256 blocks x 512 threads (1 block/CU co-resident), device-scope
// epoch grid barrier, all ODE state (y, ys, k1..k6, drive, FSAL rec1) in
// registers. 6 fp16-MFMA GEMMs per active step; dead steps break out.

typedef float f4 __attribute__((ext_vector_type(4)));
typedef float f32x4 __attribute__((ext_vector_type(4)));
typedef _Float16 half8v __attribute__((ext_vector_type(8)));
typedef _Float16 half4v __attribute__((ext_vector_type(4)));

#define AS1 __attribute__((address_space(1)))
#define AS3 __attribute__((address_space(3)))

#define NBLK 256
#define NTHR 512

#define E1c (71.0f / 57600.0f)
#define E3c (-71.0f / 16695.0f)
#define E4c (71.0f / 1920.0f)
#define E5c (-17253.0f / 339200.0f)
#define E6c (22.0f / 525.0f)
#define E7c (-1.0f / 40.0f)

__global__ void k_zero(int* bar) {
  if (threadIdx.x == 0) { bar[0] = 0; bar[16] = 0; }
}

__device__ __forceinline__ void gsync(int* arrive, int* release, int epoch) {
  __syncthreads();
  if (threadIdx.x == 0) {
    __threadfence();
    int prev = __hip_atomic_fetch_add(arrive, 1, __ATOMIC_ACQ_REL, __HIP_MEMORY_SCOPE_AGENT);
    if (prev == epoch * NBLK - 1) {
      __hip_atomic_store(release, epoch, __ATOMIC_RELEASE, __HIP_MEMORY_SCOPE_AGENT);
    } else {
      while (__hip_atomic_load(release, __ATOMIC_ACQUIRE, __HIP_MEMORY_SCOPE_AGENT) < epoch)
        __builtin_amdgcn_s_sleep(2);
    }
    __threadfence();
  }
  __syncthreads();
}

// 128x64 output tile GEMM: acc += Ain[tile rows, K] * Wh[tile cols, K]^T.
// BK=64, seg-XOR swizzled LDS (pre-swizzled global source, linear dest).
__device__ __forceinline__ void gemm_tile(const _Float16* __restrict__ Ain,
                                          const _Float16* __restrict__ Wh,
                                          int rowBase, int colBase,
                                          int tid, int wr, int wc, int lr, int lk,
                                          f32x4 acc[2][2]) {
  __shared__ _Float16 As[128 * 64];
  __shared__ _Float16 Bs[64 * 64];
#pragma unroll
  for (int m = 0; m < 2; ++m)
#pragma unroll
    for (int n = 0; n < 2; ++n)
#pragma unroll
      for (int q = 0; q < 4; ++q) acc[m][n][q] = 0.0f;

  const int lrow = tid >> 3;
  const int sw = ((tid & 7) ^ (lrow & 7)) * 8;

  for (int k0 = 0; k0 < 1024; k0 += 64) {
    if (k0) __syncthreads();
    __builtin_amdgcn_global_load_lds(
        (const AS1 void*)(Ain + (size_t)(rowBase + lrow) * 1024 + k0 + sw),
        (AS3 void*)(As + tid * 8), 16, 0, 0);
    __builtin_amdgcn_global_load_lds(
        (const AS1 void*)(Ain + (size_t)(rowBase + 64 + lrow) * 1024 + k0 + sw),
        (AS3 void*)(As + (512 + tid) * 8), 16, 0, 0);
    __builtin_amdgcn_global_load_lds(
        (const AS1 void*)(Wh + (size_t)(colBase + lrow) * 1024 + k0 + sw),
        (AS3 void*)(Bs + tid * 8), 16, 0, 0);
    __syncthreads();

    half8v af[2][2], bf[2][2];
#pragma unroll
    for (int m = 0; m < 2; ++m) {
      int r = wr * 32 + m * 16 + lr;
#pragma unroll
      for (int s = 0; s < 2; ++s)
        af[m][s] = *(const half8v*)(As + r * 64 + (((s * 4 + lk) ^ (r & 7)) * 8));
    }
#pragma unroll
    for (int n = 0; n < 2; ++n) {
      int r = wc * 32 + n * 16 + lr;
#pragma unroll
      for (int s = 0; s < 2; ++s)
        bf[n][s] = *(const half8v*)(Bs + r * 64 + (((s * 4 + lk) ^ (r & 7)) * 8));
    }
#pragma unroll
    for (int s = 0; s < 2; ++s)
#pragma unroll
      for (int m = 0; m < 2; ++m)
#pragma unroll
        for (int n = 0; n < 2; ++n)
          acc[m][n] = __builtin_amdgcn_mfma_f32_16x16x32_f16(af[m][s], bf[n][s], acc[m][n], 0, 0, 0);
  }
}

template <int S>
__device__ __forceinline__ void stage_epi(
    const f32x4 acc[2][2], float h, float* yreg, float* ysreg,
    const float* dreg, const float* itau2, const float* bias2,
    float* k1r, float* k2r, float* k3r, float* k4r, float* k5r, float* k6r,
    _Float16* __restrict__ actOut, int row0, int col0, float* errAcc) {
#pragma unroll
  for (int m = 0; m < 2; ++m)
#pragma unroll
    for (int j = 0; j < 4; ++j)
#pragma unroll
      for (int n = 0; n < 2; ++n) {
        const int e = (m * 4 + j) * 2 + n;
        float rec = acc[m][n][j];
        float yv = yreg[e];
        float ysv = (S == 1) ? yv : ysreg[e];
        float ks = itau2[n] * (dreg[e] + rec - ysv);
        if constexpr (S <= 6) {
          float nys;
          if constexpr (S == 1) {
            k1r[e] = ks; nys = yv + h * (0.2f * ks);
          } else if constexpr (S == 2) {
            k2r[e] = ks;
            nys = yv + h * ((3.0f / 40.0f) * k1r[e] + (9.0f / 40.0f) * ks);
          } else if constexpr (S == 3) {
            k3r[e] = ks;
            nys = yv + h * ((44.0f / 45.0f) * k1r[e] + (-56.0f / 15.0f) * k2r[e] +
                            (32.0f / 9.0f) * ks);
          } else if constexpr (S == 4) {
            k4r[e] = ks;
            nys = yv + h * ((19372.0f / 6561.0f) * k1r[e] + (-25360.0f / 2187.0f) * k2r[e] +
                            (64448.0f / 6561.0f) * k3r[e] + (-212.0f / 729.0f) * ks);
          } else if constexpr (S == 5) {
            k5r[e] = ks;
            nys = yv + h * ((9017.0f / 3168.0f) * k1r[e] + (-355.0f / 33.0f) * k2r[e] +
                            (46732.0f / 5247.0f) * k3r[e] + (49.0f / 176.0f) * k4r[e] +
                            (-5103.0f / 18656.0f) * ks);
          } else {
            k6r[e] = ks;
            nys = yv + h * ((35.0f / 384.0f) * k1r[e] + (500.0f / 1113.0f) * k3r[e] +
                            (125.0f / 192.0f) * k4r[e] + (-2187.0f / 6784.0f) * k5r[e] +
                            (11.0f / 84.0f) * ks);
          }
          ysreg[e] = nys;
          int b = row0 + m * 16 + j;
          actOut[(size_t)b * 1024 + col0 + n * 16] = (_Float16)tanhf(nys + bias2[n]);
        } else {
          float err = h * (E1c * k1r[e] + E3c * k3r[e] + E4c * k4r[e] +
                           E5c * k5r[e] + E6c * k6r[e] + E7c * ks);
          float sc = 1e-6f + 1e-3f * fmaxf(fabsf(yv), fabsf(ysv));
          float r = err / sc;
          *errAcc += r * r;
        }
      }
}

__global__ __launch_bounds__(NTHR, 2) void k_ode(
    const float* __restrict__ inp, const float* __restrict__ prev,
    const float* __restrict__ tau, const f4* __restrict__ W4,
    const float* __restrict__ iw, const float* __restrict__ bias,
    float* __restrict__ out, int* __restrict__ bar,
    float* __restrict__ partials, _Float16* __restrict__ Wh,
    _Float16* __restrict__ actA, _Float16* __restrict__ actB) {
  __shared__ float wsum[8];
  const int tid = (int)threadIdx.x, bid = (int)blockIdx.x;
  const int lane = tid & 63, wv = tid >> 6;
  const int wr = wv >> 1, wc = wv & 1;
  const int lr = lane & 15, lk = lane >> 4;
  const int rowBase = (bid >> 4) * 128, colBase = (bid & 15) * 64;
  const int row0 = rowBase + wr * 32 + lk * 4;
  const int col0 = colBase + wc * 32 + lr;

  // prologue: W -> fp16 cast (each block: 1024 f4 = 4096 floats)
  {
    half4v* Wh4 = (half4v*)Wh;
    int base = bid * 1024;
#pragma unroll
    for (int u = 0; u < 2; ++u) {
      int idx = base + u * NTHR + tid;
      f4 w = W4[idx];
      half4v o;
#pragma unroll
      for (int j = 0; j < 4; ++j) o[j] = (_Float16)w[j];
      Wh4[idx] = o;
    }
  }

  float yreg[16], ysreg[16], dreg[16];
  float k1r[16], k2r[16], k3r[16], k4r[16], k5r[16], k6r[16];
  f32x4 rec1a[2][2];
  f32x4 acc[2][2];
  float itau2[2], bias2[2];
#pragma unroll
  for (int n = 0; n < 2; ++n) {
    itau2[n] = 1.0f / tau[col0 + n * 16];
    bias2[n] = bias[col0 + n * 16];
  }
#pragma unroll
  for (int m = 0; m < 2; ++m)
#pragma unroll
    for (int j = 0; j < 4; ++j)
#pragma unroll
      for (int n = 0; n < 2; ++n) {
        const int e = (m * 4 + j) * 2 + n;
        int b = row0 + m * 16 + j;
        int i = col0 + n * 16;
        size_t off = (size_t)b * 1024 + i;
        float yv = prev[off];
        yreg[e] = yv;
        ysreg[e] = yv;
        dreg[e] = inp[off] * iw[i];
        actA[off] = (_Float16)tanhf(yv + bias2[n]);
      }

  int* arrive = bar;
  int* release = bar + 16;
  int epoch = 1;
  gsync(arrive, release, epoch);

  // initial rec1 = W * tanh(y0 + b)
  gemm_tile(actA, Wh, rowBase, colBase, tid, wr, wc, lr, lk, rec1a);

  float t = 0.0f, dtv = 0.1f;
#pragma unroll 1
  for (int s = 0; s < 40; ++s) {
    if (t >= 1.0f - 1e-7f) break;
    float h = fminf(dtv, 1.0f - t);

    // P1: register-only (FSAL rec1), writes act2 -> actB
    stage_epi<1>(rec1a, h, yreg, ysreg, dreg, itau2, bias2,
                 k1r, k2r, k3r, k4r, k5r, k6r, actB, row0, col0, nullptr);
    ++epoch; gsync(arrive, release, epoch);

    gemm_tile(actB, Wh, rowBase, colBase, tid, wr, wc, lr, lk, acc);
    stage_epi<2>(acc, h, yreg, ysreg, dreg, itau2, bias2,
                 k1r, k2r, k3r, k4r, k5r, k6r, actA, row0, col0, nullptr);
    ++epoch; gsync(arrive, release, epoch);

    gemm_tile(actA, Wh, rowBase, colBase, tid, wr, wc, lr, lk, acc);
    stage_epi<3>(acc, h, yreg, ysreg, dreg, itau2, bias2,
                 k1r, k2r, k3r, k4r, k5r, k6r, actB, row0, col0, nullptr);
    ++epoch; gsync(arrive, release, epoch);

    gemm_tile(actB, Wh, rowBase, colBase, tid, wr, wc, lr, lk, acc);
    stage_epi<4>(acc, h, yreg, ysreg, dreg, itau2, bias2,
                 k1r, k2r, k3r, k4r, k5r, k6r, actA, row0, col0, nullptr);
    ++epoch; gsync(arrive, release, epoch);

    gemm_tile(actA, Wh, rowBase, colBase, tid, wr, wc, lr, lk, acc);
    stage_epi<5>(acc, h, yreg, ysreg, dreg, itau2, bias2,
                 k1r, k2r, k3r, k4r, k5r, k6r, actB, row0, col0, nullptr);
    ++epoch; gsync(arrive, release, epoch);

    gemm_tile(actB, Wh, rowBase, colBase, tid, wr, wc, lr, lk, acc);
    stage_epi<6>(acc, h, yreg, ysreg, dreg, itau2, bias2,
                 k1r, k2r, k3r, k4r, k5r, k6r, actA, row0, col0, nullptr);
    ++epoch; gsync(arrive, release, epoch);

    // P7: k7 GEMM on act7 (=actA); acc kept as FSAL rec candidate
    gemm_tile(actA, Wh, rowBase, colBase, tid, wr, wc, lr, lk, acc);
    float errAcc = 0.0f;
    stage_epi<7>(acc, h, yreg, ysreg, dreg, itau2, bias2,
                 k1r, k2r, k3r, k4r, k5r, k6r, nullptr, row0, col0, &errAcc);
#pragma unroll
    for (int o = 32; o > 0; o >>= 1) errAcc += __shfl_down(errAcc, o, 64);
    if (lane == 0) wsum[wv] = errAcc;
    __syncthreads();
    if (tid == 0) {
      float sblk = 0.0f;
#pragma unroll
      for (int w = 0; w < 8; ++w) sblk += wsum[w];
      partials[s * NBLK + bid] = sblk;
    }
    ++epoch; gsync(arrive, release, epoch);

    // redundant, deterministic controller in every block
    double sd = 0.0;
#pragma unroll 1
    for (int p = 0; p < NBLK; ++p) sd += (double)partials[s * NBLK + p];
    float enorm = fmaxf(sqrtf((float)(sd / (double)(2048.0 * 1024.0))), 1e-10f);
    if (enorm <= 1.0f) {
      t = t + h;
#pragma unroll
      for (int e = 0; e < 16; ++e) yreg[e] = ysreg[e];
#pragma unroll
      for (int m = 0; m < 2; ++m)
#pragma unroll
        for (int n = 0; n < 2; ++n) rec1a[m][n] = acc[m][n];
    }
    float factor = fminf(fmaxf(0.9f * powf(enorm, -0.2f), 0.2f), 5.0f);
    dtv = dtv * factor;
  }

  // write final state
#pragma unroll
  for (int m = 0; m < 2; ++m)
#pragma unroll
    for (int j = 0; j < 4; ++j)
#pragma unroll
      for (int n = 0; n < 2; ++n) {
        const int e = (m * 4 + j) * 2 + n;
        int b = row0 + m * 16 + j;
        out[(size_t)b * 1024 + col0 + n * 16] = yreg[e];
      }
}

extern "C" void kernel_launch(void* const* d_in, const int* in_sizes, int n_in,
                              void* d_out, int out_size, void* d_ws, size_t ws_size,
                              hipStream_t stream) {
  const float* inp = (const float*)d_in[0];
  const float* prev = (const float*)d_in[1];
  const float* tau = (const float*)d_in[2];
  const f4* W4 = (const f4*)d_in[3];
  const float* iw = (const float*)d_in[4];
  const float* bias = (const float*)d_in[5];
  float* out = (float*)d_out;

  char* ws = (char*)d_ws;
  int* bar = (int*)ws;                             // [0]=arrive, [16]=release
  float* partials = (float*)(ws + 256);            // 40*256 floats
  _Float16* Wh = (_Float16*)(ws + 64 * 1024);      // 2 MB
  _Float16* actA = (_Float16*)(ws + 64 * 1024 + 2 * 1024 * 1024);  // 4 MB
  _Float16* actB = (_Float16*)(ws + 64 * 1024 + 6 * 1024 * 1024);  // 4 MB

  k_zero<<<1, 64, 0, stream>>>(bar);
  k_ode<<<NBLK, NTHR, 0, stream>>>(inp, prev, tau, W4, iw, bias, out,
                                   bar, partials, Wh, actA, actB);
}

// Round 4
// 1383.715 us; speedup vs baseline: 1.2181x; 1.2181x over previous
//
#include <hip/hip_runtime.h>
#include <math.h>

// CTRNN + adaptive DOPRI5 (B=2048, N=1024). Round 4: persistent kernel,
// batch-sliced decomposition. 256 blocks x 512 thr, each owns 16 rows x 512
// cols. Own act half lives in LDS; partner half (16KB) exchanged via
// same-XCD L2 with a per-pair handshake. W (2MB fp16) streamed from L2.
// State (y, ys, k1..k7, drive) fully register-resident. FSAL: k1=k7 on
// accept -> 6 GEMM stages per step, no GEMM for stage 1.

typedef float f4 __attribute__((ext_vector_type(4)));
typedef float f32x4 __attribute__((ext_vector_type(4)));
typedef _Float16 half8v __attribute__((ext_vector_type(8)));
typedef _Float16 half4v __attribute__((ext_vector_type(4)));
typedef _Float16 half2v __attribute__((ext_vector_type(2)));

#define NBLK 256
#define NTHR 512

#define E1c (71.0f / 57600.0f)
#define E3c (-71.0f / 16695.0f)
#define E4c (71.0f / 1920.0f)
#define E5c (-17253.0f / 339200.0f)
#define E6c (22.0f / 525.0f)
#define E7c (-1.0f / 40.0f)

__global__ void k_zero(int* bar) {
  int i = (int)threadIdx.x;
  if (i == 0) { bar[0] = 0; bar[16] = 0; }
  bar[32 + i] = 0;  // pair flags[256]
}

__device__ __forceinline__ void gsync(int* arrive, int* release, int epoch) {
  __syncthreads();
  if (threadIdx.x == 0) {
    __threadfence();
    int prev = __hip_atomic_fetch_add(arrive, 1, __ATOMIC_ACQ_REL, __HIP_MEMORY_SCOPE_AGENT);
    if (prev == epoch * NBLK - 1) {
      __hip_atomic_store(release, epoch, __ATOMIC_RELEASE, __HIP_MEMORY_SCOPE_AGENT);
    } else {
      while (__hip_atomic_load(release, __ATOMIC_ACQUIRE, __HIP_MEMORY_SCOPE_AGENT) < epoch)
        __builtin_amdgcn_s_sleep(2);
    }
    __threadfence();
  }
  __syncthreads();
}

__device__ __forceinline__ void psync(int* flags, int bid, int partner, int cnt) {
  __syncthreads();
  if (threadIdx.x == 0) {
    __threadfence();
    __hip_atomic_store(&flags[bid], cnt, __ATOMIC_RELEASE, __HIP_MEMORY_SCOPE_AGENT);
    while (__hip_atomic_load(&flags[partner], __ATOMIC_ACQUIRE, __HIP_MEMORY_SCOPE_AGENT) < cnt)
      __builtin_amdgcn_s_sleep(1);
  }
  __syncthreads();
}

__device__ __forceinline__ float ftanh(float x) {
  x = fminf(fmaxf(x, -9.0f), 9.0f);
  float e = __expf(2.0f * x);
  return (e - 1.0f) / (e + 1.0f);
}

// rec[16 rows x 64 cols/wave] = act[16,1024] @ W[cols,1024]^T.
// A: own half from swizzled LDS, partner half from global (L2). B: direct
// global loads from L2-resident Wh.
__device__ __forceinline__ void gemm_stage(
    const char* ldsA, const _Float16* __restrict__ pA,
    const _Float16* w0, const _Float16* w1,
    const _Float16* w2, const _Float16* w3,
    int ownK0, int partK0, int lr, int lk, f32x4 acc[4]) {
#pragma unroll
  for (int tl = 0; tl < 4; ++tl)
#pragma unroll
    for (int q = 0; q < 4; ++q) acc[tl][q] = 0.0f;
  const char* ldsRow = ldsA + lr * 1024;
  const int c7 = lr & 7;
  const _Float16 *o0 = w0 + ownK0, *o1 = w1 + ownK0, *o2 = w2 + ownK0, *o3 = w3 + ownK0;
#pragma unroll 2
  for (int kk = 0; kk < 512; kk += 32) {
    half8v a = *(const half8v*)(ldsRow + ((((kk >> 3) | lk) ^ c7) << 4));
    half8v b0 = *(const half8v*)(o0 + kk);
    half8v b1 = *(const half8v*)(o1 + kk);
    half8v b2 = *(const half8v*)(o2 + kk);
    half8v b3 = *(const half8v*)(o3 + kk);
    acc[0] = __builtin_amdgcn_mfma_f32_16x16x32_f16(a, b0, acc[0], 0, 0, 0);
    acc[1] = __builtin_amdgcn_mfma_f32_16x16x32_f16(a, b1, acc[1], 0, 0, 0);
    acc[2] = __builtin_amdgcn_mfma_f32_16x16x32_f16(a, b2, acc[2], 0, 0, 0);
    acc[3] = __builtin_amdgcn_mfma_f32_16x16x32_f16(a, b3, acc[3], 0, 0, 0);
  }
  const _Float16 *p0 = w0 + partK0, *p1 = w1 + partK0, *p2 = w2 + partK0, *p3 = w3 + partK0;
#pragma unroll 2
  for (int kk = 0; kk < 512; kk += 32) {
    half8v a = *(const half8v*)(pA + kk);
    half8v b0 = *(const half8v*)(p0 + kk);
    half8v b1 = *(const half8v*)(p1 + kk);
    half8v b2 = *(const half8v*)(p2 + kk);
    half8v b3 = *(const half8v*)(p3 + kk);
    acc[0] = __builtin_amdgcn_mfma_f32_16x16x32_f16(a, b0, acc[0], 0, 0, 0);
    acc[1] = __builtin_amdgcn_mfma_f32_16x16x32_f16(a, b1, acc[1], 0, 0, 0);
    acc[2] = __builtin_amdgcn_mfma_f32_16x16x32_f16(a, b2, acc[2], 0, 0, 0);
    acc[3] = __builtin_amdgcn_mfma_f32_16x16x32_f16(a, b3, acc[3], 0, 0, 0);
  }
}

template <int S>
__device__ __forceinline__ void stage_epi(
    const f32x4 acc[4], float h,
    float* y, float* ys, const half2v* dh,
    float* k1, float* k2, float* k3, float* k4, float* k5, float* k6, float* k7,
    const float* itau4, const float* bias4,
    char* ldsW, _Float16* gW, int lr, int lk, int wv, float* errAcc) {
#pragma unroll
  for (int tl = 0; tl < 4; ++tl) {
#pragma unroll
    for (int j = 0; j < 4; ++j) {
      const int e = tl * 4 + j;
      const int row = lk * 4 + j;
      float yv = y[e];
      float ks;
      if constexpr (S == 1) {
        ks = k1[e];
      } else {
        float rec = acc[tl][j];
        float ysv = ys[e];
        ks = itau4[tl] * ((float)dh[e >> 1][e & 1] + rec - ysv);
      }
      if constexpr (S <= 6) {
        float nys;
        if constexpr (S == 1) {
          nys = yv + h * (0.2f * ks);
        } else if constexpr (S == 2) {
          k2[e] = ks;
          nys = yv + h * ((3.0f / 40.0f) * k1[e] + (9.0f / 40.0f) * ks);
        } else if constexpr (S == 3) {
          k3[e] = ks;
          nys = yv + h * ((44.0f / 45.0f) * k1[e] + (-56.0f / 15.0f) * k2[e] +
                          (32.0f / 9.0f) * ks);
        } else if constexpr (S == 4) {
          k4[e] = ks;
          nys = yv + h * ((19372.0f / 6561.0f) * k1[e] + (-25360.0f / 2187.0f) * k2[e] +
                          (64448.0f / 6561.0f) * k3[e] + (-212.0f / 729.0f) * ks);
        } else if constexpr (S == 5) {
          k5[e] = ks;
          nys = yv + h * ((9017.0f / 3168.0f) * k1[e] + (-355.0f / 33.0f) * k2[e] +
                          (46732.0f / 5247.0f) * k3[e] + (49.0f / 176.0f) * k4[e] +
                          (-5103.0f / 18656.0f) * ks);
        } else {
          k6[e] = ks;
          nys = yv + h * ((35.0f / 384.0f) * k1[e] + (500.0f / 1113.0f) * k3[e] +
                          (125.0f / 192.0f) * k4[e] + (-2187.0f / 6784.0f) * k5[e] +
                          (11.0f / 84.0f) * ks);
        }
        ys[e] = nys;
        float av = ftanh(nys + bias4[tl]);
        int colLoc = wv * 64 + tl * 16 + lr;
        int sw = (colLoc >> 3) ^ (row & 7);
        *(_Float16*)(ldsW + row * 1024 + sw * 16 + (colLoc & 7) * 2) = (_Float16)av;
        gW[row * 512 + colLoc] = (_Float16)av;
      } else {
        k7[e] = ks;
        float err = h * (E1c * k1[e] + E3c * k3[e] + E4c * k4[e] +
                         E5c * k5[e] + E6c * k6[e] + E7c * ks);
        float sc = 1e-6f + 1e-3f * fmaxf(fabsf(yv), fabsf(ys[e]));
        float r = err / sc;
        *errAcc += r * r;
      }
    }
  }
}

__global__ __launch_bounds__(NTHR, 2) void k_ode(
    const float* __restrict__ inp, const float* __restrict__ prev,
    const float* __restrict__ tau, const f4* __restrict__ W4,
    const float* __restrict__ iw, const float* __restrict__ bias,
    float* __restrict__ out, int* __restrict__ bar,
    float* __restrict__ partials, _Float16* __restrict__ Wh,
    _Float16* __restrict__ actg) {
  __shared__ _Float16 actL[2][16][512];   // 32 KB, XOR-swizzled cols
  __shared__ float wsum[8];

  const int tid = (int)threadIdx.x, bid = (int)blockIdx.x;
  const int lane = tid & 63, wv = tid >> 6;
  const int lr = lane & 15, lk = lane >> 4;
  const int rowGroup = (bid & 7) | ((bid >> 4) << 3);  // 0..127
  const int colHalf = (bid >> 3) & 1;
  const int partner = bid ^ 8;                          // same XCD (bid%8)
  const int rowBase = rowGroup * 16;
  const int colBase = colHalf * 512;
  const int ownK0 = colBase, partK0 = colBase ^ 512;

  int* arrive = bar;
  int* release = bar + 16;
  int* flags = bar + 32;

  // --- W -> fp16 cast (each block casts its 4096-float slice) ---
  {
    half4v* Wh4 = (half4v*)Wh;
    int base = bid * 1024;
#pragma unroll
    for (int u = 0; u < 2; ++u) {
      int idx = base + u * NTHR + tid;
      f4 w = W4[idx];
      half4v o;
#pragma unroll
      for (int j = 0; j < 4; ++j) o[j] = (_Float16)w[j];
      Wh4[idx] = o;
    }
  }

  // --- pointers ---
  _Float16* gw[2];
  const _Float16* pact[2];
#pragma unroll
  for (int b = 0; b < 2; ++b) {
    gw[b] = actg + ((size_t)(b * 2 + colHalf) * 2048 + rowBase) * 512;
    pact[b] = actg + ((size_t)(b * 2 + (colHalf ^ 1)) * 2048 + rowBase) * 512 +
              lr * 512 + lk * 8;
  }
  const _Float16* w0 = Wh + (size_t)(colBase + wv * 64 + 0 * 16 + lr) * 1024 + lk * 8;
  const _Float16* w1 = Wh + (size_t)(colBase + wv * 64 + 1 * 16 + lr) * 1024 + lk * 8;
  const _Float16* w2 = Wh + (size_t)(colBase + wv * 64 + 2 * 16 + lr) * 1024 + lk * 8;
  const _Float16* w3 = Wh + (size_t)(colBase + wv * 64 + 3 * 16 + lr) * 1024 + lk * 8;
  char* lds0 = (char*)&actL[0][0][0];
  char* lds1 = lds0 + 16384;

  // --- state init + act1 -> buf1 ---
  float y[16], ysr[16];
  half2v dh[8];
  float itau4[4], bias4[4];
  float k1r[16], k2r[16], k3r[16], k4r[16], k5r[16], k6r[16], k7r[16];
#pragma unroll
  for (int tl = 0; tl < 4; ++tl) {
    int col = colBase + wv * 64 + tl * 16 + lr;
    itau4[tl] = 1.0f / tau[col];
    bias4[tl] = bias[col];
  }
#pragma unroll
  for (int tl = 0; tl < 4; ++tl) {
#pragma unroll
    for (int j = 0; j < 4; ++j) {
      const int e = tl * 4 + j;
      const int row = lk * 4 + j;
      int colLoc = wv * 64 + tl * 16 + lr;
      int col = colBase + colLoc;
      size_t off = (size_t)(rowBase + row) * 1024 + col;
      float yv = prev[off];
      y[e] = yv;
      ysr[e] = yv;
      dh[e >> 1][e & 1] = (_Float16)(inp[off] * iw[col]);
      float av = ftanh(yv + bias4[tl]);
      int sw = (colLoc >> 3) ^ (row & 7);
      *(_Float16*)(lds1 + row * 1024 + sw * 16 + (colLoc & 7) * 2) = (_Float16)av;
      gw[1][row * 512 + colLoc] = (_Float16)av;
    }
  }

  int ep = 1;
  gsync(arrive, release, ep);   // W cast + act1 visible everywhere

  f32x4 acc[4];
  gemm_stage(lds1, pact[1], w0, w1, w2, w3, ownK0, partK0, lr, lk, acc);
#pragma unroll
  for (int tl = 0; tl < 4; ++tl)
#pragma unroll
    for (int j = 0; j < 4; ++j) {
      const int e = tl * 4 + j;
      k1r[e] = itau4[tl] * ((float)dh[e >> 1][e & 1] + acc[tl][j] - y[e]);
    }

  float t = 0.0f, dtv = 0.1f;
  int pcnt = 0;
#pragma unroll 1
  for (int s = 0; s < 40; ++s) {
    if (t >= 1.0f - 1e-7f) break;
    float h = fminf(dtv, 1.0f - t);

    stage_epi<1>(acc, h, y, ysr, dh, k1r, k2r, k3r, k4r, k5r, k6r, k7r,
                 itau4, bias4, lds0, gw[0], lr, lk, wv, nullptr);
    psync(flags, bid, partner, ++pcnt);
    gemm_stage(lds0, pact[0], w0, w1, w2, w3, ownK0, partK0, lr, lk, acc);
    stage_epi<2>(acc, h, y, ysr, dh, k1r, k2r, k3r, k4r, k5r, k6r, k7r,
                 itau4, bias4, lds1, gw[1], lr, lk, wv, nullptr);
    psync(flags, bid, partner, ++pcnt);
    gemm_stage(lds1, pact[1], w0, w1, w2, w3, ownK0, partK0, lr, lk, acc);
    stage_epi<3>(acc, h, y, ysr, dh, k1r, k2r, k3r, k4r, k5r, k6r, k7r,
                 itau4, bias4, lds0, gw[0], lr, lk, wv, nullptr);
    psync(flags, bid, partner, ++pcnt);
    gemm_stage(lds0, pact[0], w0, w1, w2, w3, ownK0, partK0, lr, lk, acc);
    stage_epi<4>(acc, h, y, ysr, dh, k1r, k2r, k3r, k4r, k5r, k6r, k7r,
                 itau4, bias4, lds1, gw[1], lr, lk, wv, nullptr);
    psync(flags, bid, partner, ++pcnt);
    gemm_stage(lds1, pact[1], w0, w1, w2, w3, ownK0, partK0, lr, lk, acc);
    stage_epi<5>(acc, h, y, ysr, dh, k1r, k2r, k3r, k4r, k5r, k6r, k7r,
                 itau4, bias4, lds0, gw[0], lr, lk, wv, nullptr);
    psync(flags, bid, partner, ++pcnt);
    gemm_stage(lds0, pact[0], w0, w1, w2, w3, ownK0, partK0, lr, lk, acc);
    stage_epi<6>(acc, h, y, ysr, dh, k1r, k2r, k3r, k4r, k5r, k6r, k7r,
                 itau4, bias4, lds1, gw[1], lr, lk, wv, nullptr);
    psync(flags, bid, partner, ++pcnt);
    gemm_stage(lds1, pact[1], w0, w1, w2, w3, ownK0, partK0, lr, lk, acc);
    float errAcc = 0.0f;
    stage_epi<7>(acc, h, y, ysr, dh, k1r, k2r, k3r, k4r, k5r, k6r, k7r,
                 itau4, bias4, lds0, gw[0], lr, lk, wv, &errAcc);

#pragma unroll
    for (int o = 32; o > 0; o >>= 1) errAcc += __shfl_down(errAcc, o, 64);
    if (lane == 0) wsum[wv] = errAcc;
    __syncthreads();
    if (tid == 0) {
      float sblk = 0.0f;
#pragma unroll
      for (int w = 0; w < 8; ++w) sblk += wsum[w];
      partials[s * NBLK + bid] = sblk;
    }
    ++ep;
    gsync(arrive, release, ep);

    double sd = 0.0;
#pragma unroll 1
    for (int p = 0; p < NBLK; ++p) sd += (double)partials[s * NBLK + p];
    float enorm = fmaxf(sqrtf((float)(sd / (2048.0 * 1024.0))), 1e-10f);
    if (enorm <= 1.0f) {
      t = t + h;
#pragma unroll
      for (int e = 0; e < 16; ++e) { y[e] = ysr[e]; k1r[e] = k7r[e]; }
    }
    float factor = fminf(fmaxf(0.9f * powf(enorm, -0.2f), 0.2f), 5.0f);
    dtv = dtv * factor;
  }

  // --- final output ---
#pragma unroll
  for (int tl = 0; tl < 4; ++tl)
#pragma unroll
    for (int j = 0; j < 4; ++j) {
      const int e = tl * 4 + j;
      const int row = lk * 4 + j;
      int col = colBase + wv * 64 + tl * 16 + lr;
      out[(size_t)(rowBase + row) * 1024 + col] = y[e];
    }
}

extern "C" void kernel_launch(void* const* d_in, const int* in_sizes, int n_in,
                              void* d_out, int out_size, void* d_ws, size_t ws_size,
                              hipStream_t stream) {
  const float* inp = (const float*)d_in[0];
  const float* prev = (const float*)d_in[1];
  const float* tau = (const float*)d_in[2];
  const f4* W4 = (const f4*)d_in[3];
  const float* iw = (const float*)d_in[4];
  const float* bias = (const float*)d_in[5];
  float* out = (float*)d_out;

  char* ws = (char*)d_ws;
  const size_t MB = 1024 * 1024;
  int* bar = (int*)ws;                           // arrive/release/flags
  float* partials = (float*)(ws + 4096);         // 40*256 floats
  _Float16* Wh = (_Float16*)(ws + 64 * 1024);    // 2 MB
  _Float16* actg = (_Float16*)(ws + 64 * 1024 + 2 * MB);  // 8 MB (2 buf x 2 half)

  k_zero<<<1, 256, 0, stream>>>(bar);
  k_ode<<<NBLK, NTHR, 0, stream>>>(inp, prev, tau, W4, iw, bias, out,
                                   bar, partials, Wh, actg);
}